// Round 1
// baseline (781.085 us; speedup 1.0000x reference)
//
#include <hip/hip_runtime.h>
#include <hip/hip_bf16.h>

#define DEVI __device__ __forceinline__

typedef __attribute__((ext_vector_type(4))) float f32x4;
typedef __attribute__((ext_vector_type(8))) short s16x8;
typedef __attribute__((ext_vector_type(4))) short s16x4;

static constexpr int B_   = 2;
static constexpr int T_   = 2048;
static constexpr int D_   = 2048;
static constexpr int NH_  = 16;
static constexpr int NKV_ = 4;
static constexpr int HD_  = 128;
static constexpr int M_   = B_ * T_;            // 4096 tokens
static constexpr int NQK  = NH_ * HD_ * 2;      // 4096 (q+gate)
static constexpr int NKC  = NKV_ * HD_;         // 512
static constexpr int NTOT = NQK + 2 * NKC;      // 5120
static constexpr float SCALE_ = 0.08838834764831845f; // HD^-0.5

DEVI short f2bf(float f) {
    __hip_bfloat16 h = __float2bfloat16(f);
    return __builtin_bit_cast(short, h);
}
DEVI float bf2f(short s) {
    unsigned int u = ((unsigned int)(unsigned short)s) << 16;
    return __builtin_bit_cast(float, u);
}
DEVI void store_out(short* p, float v) { *p = f2bf(v); }
DEVI void store_out(float* p, float v) { *p = v; }

DEVI f32x4 mfma16(s16x8 a, s16x8 b, f32x4 c) {
    return __builtin_amdgcn_mfma_f32_16x16x32_bf16(a, b, c, 0, 0, 0);
}

DEVI void gload_lds16(const void* g, void* l) {
    __builtin_amdgcn_global_load_lds(
        (const __attribute__((address_space(1))) void*)g,
        (__attribute__((address_space(3))) void*)l,
        16, 0, 0);
}

// ---------------- cast fp32 -> bf16 (vector x4) ----------------
__global__ void cast_f32_bf16(const float* __restrict__ in, short* __restrict__ out) {
    int i = (blockIdx.x * 256 + threadIdx.x) << 2;
    f32x4 v = *(const f32x4*)(in + i);
    s16x4 o;
#pragma unroll
    for (int j = 0; j < 4; ++j) o[j] = f2bf(v[j]);
    *(s16x4*)(out + i) = o;
}

// ---------------- transpose + cast: src fp32 (R,C) -> dst bf16 (C,R) ----------------
__global__ void transpose_cast(const float* __restrict__ src, short* __restrict__ dst,
                               int R, int C) {
    __shared__ float tile[32][33];
    int c0 = blockIdx.x << 5, r0 = blockIdx.y << 5;
    int tx = threadIdx.x, ty = threadIdx.y; // 32 x 8
#pragma unroll
    for (int i = 0; i < 32; i += 8)
        tile[ty + i][tx] = src[(long)(r0 + ty + i) * C + c0 + tx];
    __syncthreads();
#pragma unroll
    for (int i = 0; i < 32; i += 8)
        dst[(long)(c0 + ty + i) * R + r0 + tx] = f2bf(tile[tx][ty + i]);
}

// ---------------- GEMM: A(M,K) bf16 row-major  @  Bt(N,K) bf16 row-major -> C(M,N) ----------------
template <typename OUT>
__global__ __launch_bounds__(256, 2) void gemm_bf16(
    const short* __restrict__ A, const short* __restrict__ Bt,
    OUT* __restrict__ C, int M, int N, int K) {
    __shared__ __align__(16) short Asm[2][128 * 32];
    __shared__ __align__(16) short Bsm[2][128 * 32];
    int tid = threadIdx.x;
    int nbx = N >> 7;
    int bx = blockIdx.x % nbx, by = blockIdx.x / nbx;
    int row0 = by << 7, col0 = bx << 7;
    int lane = tid & 63, wave = tid >> 6;
    int wr = (wave >> 1) << 6, wc = (wave & 1) << 6;
    int g = lane >> 4, rl = lane & 15;
    int srow = tid >> 2, scol = (tid & 3) << 3;
    const short* Ag = A + (long)(row0 + srow) * K + scol;
    const short* Bg = Bt + (long)(col0 + srow) * K + scol;

    f32x4 acc[4][4];
#pragma unroll
    for (int i = 0; i < 4; ++i)
#pragma unroll
        for (int j = 0; j < 4; ++j) acc[i][j] = f32x4{0.f, 0.f, 0.f, 0.f};

    auto stage = [&](int buf, int kt) {
        int ko = kt << 5;
        gload_lds16(Ag + ko,            &Asm[buf][tid * 8]);
        gload_lds16(Ag + (K << 6) + ko, &Asm[buf][(tid + 256) * 8]);
        gload_lds16(Bg + ko,            &Bsm[buf][tid * 8]);
        gload_lds16(Bg + (K << 6) + ko, &Bsm[buf][(tid + 256) * 8]);
    };

    int KT = K >> 5;
    stage(0, 0);
    for (int kt = 0; kt < KT; ++kt) {
        __syncthreads();
        int buf = kt & 1;
        if (kt + 1 < KT) stage(buf ^ 1, kt + 1);
        const short* As = &Asm[buf][0];
        const short* Bs = &Bsm[buf][0];
        s16x8 af[4], bfr[4];
#pragma unroll
        for (int i = 0; i < 4; ++i) {
            af[i]  = *(const s16x8*)(As + (wr + i * 16 + rl) * 32 + g * 8);
            bfr[i] = *(const s16x8*)(Bs + (wc + i * 16 + rl) * 32 + g * 8);
        }
#pragma unroll
        for (int i = 0; i < 4; ++i)
#pragma unroll
            for (int j = 0; j < 4; ++j)
                acc[i][j] = mfma16(af[i], bfr[j], acc[i][j]);
    }
#pragma unroll
    for (int i = 0; i < 4; ++i)
#pragma unroll
        for (int j = 0; j < 4; ++j)
#pragma unroll
            for (int r = 0; r < 4; ++r) {
                int row = row0 + wr + i * 16 + 4 * g + r;
                int col = col0 + wc + j * 16 + rl;
                store_out(&C[(long)row * N + col], acc[i][j][r]);
            }
}

// ---------------- RMSNorm + RoPE for q and k heads ----------------
__global__ void postproc(const short* __restrict__ qkv, const float* __restrict__ cosp,
                         const float* __restrict__ sinp, const float* __restrict__ qw,
                         const float* __restrict__ kw, short* __restrict__ Q,
                         short* __restrict__ K) {
    int task = blockIdx.x * 4 + (threadIdx.x >> 6); // B*T*20 tasks
    int lane = threadIdx.x & 63;
    int bt = task / 20, sub = task - bt * 20;
    int b = bt >> 11, t = bt & (T_ - 1);
    bool isq = sub < 16;
    int h = isq ? sub : sub - 16;
    const short* src = qkv + (long)bt * NTOT + (isq ? h * 256 : NQK + h * HD_);
    const float* w = isq ? qw : kw;
    float x0 = bf2f(src[lane]);
    float x1 = bf2f(src[lane + 64]);
    float ss = x0 * x0 + x1 * x1;
    ss += __shfl_xor(ss, 32); ss += __shfl_xor(ss, 16); ss += __shfl_xor(ss, 8);
    ss += __shfl_xor(ss, 4);  ss += __shfl_xor(ss, 2);  ss += __shfl_xor(ss, 1);
    float rn = rsqrtf(ss * (1.0f / 128.0f) + 1e-6f);
    x0 *= rn * w[lane];
    x1 *= rn * w[lane + 64];
    float c0 = cosp[bt * HD_ + lane], c1 = cosp[bt * HD_ + lane + 64];
    float s0 = sinp[bt * HD_ + lane], s1 = sinp[bt * HD_ + lane + 64];
    float y0 = x0 * c0 - x1 * s0;
    float y1 = x1 * c1 + x0 * s1;
    short* dst;
    if (isq) {
        y0 *= SCALE_; y1 *= SCALE_;
        dst = Q + ((long)(b * NH_ + h) * T_ + t) * HD_;
    } else {
        dst = K + ((long)(b * NKV_ + h) * T_ + t) * HD_;
    }
    dst[lane]      = f2bf(y0);
    dst[lane + 64] = f2bf(y1);
}

// ---------------- V transpose: qkv v-cols -> VT (B,NKV,HD,T) ----------------
__global__ void transpose_v(const short* __restrict__ qkv, short* __restrict__ VT) {
    __shared__ short tile[32][33];
    int bh = blockIdx.z;
    int b = bh >> 2, h = bh & 3;
    int t0 = blockIdx.x << 5, d0 = blockIdx.y << 5;
    int tx = threadIdx.x, ty = threadIdx.y; // 32 x 8
    const short* src = qkv + (long)b * T_ * NTOT + NQK + NKC + h * HD_;
#pragma unroll
    for (int i = 0; i < 32; i += 8)
        tile[ty + i][tx] = src[(long)(t0 + ty + i) * NTOT + d0 + tx];
    __syncthreads();
    short* dst = VT + ((long)(b * NKV_ + h) * HD_ + d0) * T_ + t0;
#pragma unroll
    for (int i = 0; i < 32; i += 8)
        dst[(long)(ty + i) * T_ + tx] = tile[tx][ty + i];
}

// ---------------- causal GQA flash attention + sigmoid gate ----------------
__global__ __launch_bounds__(256) void fattn(
    const short* __restrict__ Q, const short* __restrict__ K,
    const short* __restrict__ VT, const short* __restrict__ qkv,
    short* __restrict__ AG) {
    __shared__ __align__(16) short Pl[4][16 * 32];
    int idx = blockIdx.x;
    int qt = idx & 31;          // T/64 tiles
    int h = (idx >> 5) & 15;
    int b = idx >> 9;
    int lane = threadIdx.x & 63, wave = threadIdx.x >> 6;
    int qbase = qt * 64 + wave * 16;
    int kvh = h >> 2;
    const short* Qp = Q + ((long)(b * NH_ + h) * T_ + qbase) * HD_;
    const short* Kp = K + (long)(b * NKV_ + kvh) * T_ * HD_;
    const short* Vp = VT + (long)(b * NKV_ + kvh) * HD_ * T_;
    int g = lane >> 4, rl = lane & 15;

    s16x8 qf[4];
#pragma unroll
    for (int c = 0; c < 4; ++c)
        qf[c] = *(const s16x8*)(Qp + rl * HD_ + c * 32 + g * 8);

    f32x4 o[8];
#pragma unroll
    for (int dt = 0; dt < 8; ++dt) o[dt] = f32x4{0.f, 0.f, 0.f, 0.f};
    float m[4] = {-1e30f, -1e30f, -1e30f, -1e30f};
    float l[4] = {0.f, 0.f, 0.f, 0.f};
    short* Pw = &Pl[wave][0];

    int ntiles = (qbase + 47) >> 5;
    for (int kt = 0; kt < ntiles; ++kt) {
        int k0 = kt * 32;
        f32x4 s0 = {0.f, 0.f, 0.f, 0.f}, s1 = {0.f, 0.f, 0.f, 0.f};
#pragma unroll
        for (int c = 0; c < 4; ++c) {
            s16x8 kf0 = *(const s16x8*)(Kp + (long)(k0 + rl) * HD_ + c * 32 + g * 8);
            s16x8 kf1 = *(const s16x8*)(Kp + (long)(k0 + 16 + rl) * HD_ + c * 32 + g * 8);
            s0 = mfma16(qf[c], kf0, s0);
            s1 = mfma16(qf[c], kf1, s1);
        }
        if (k0 + 31 > qbase) { // boundary tile: causal mask
#pragma unroll
            for (int r = 0; r < 4; ++r) {
                int qi = qbase + 4 * g + r;
                if (k0 + rl > qi)      s0[r] = -1e30f;
                if (k0 + 16 + rl > qi) s1[r] = -1e30f;
            }
        }
        float fr[4];
#pragma unroll
        for (int r = 0; r < 4; ++r) {
            float v = fmaxf(s0[r], s1[r]);
            v = fmaxf(v, __shfl_xor(v, 1));
            v = fmaxf(v, __shfl_xor(v, 2));
            v = fmaxf(v, __shfl_xor(v, 4));
            v = fmaxf(v, __shfl_xor(v, 8));
            float mn = fmaxf(m[r], v);
            fr[r] = __expf(m[r] - mn);
            m[r] = mn;
            s0[r] = __expf(s0[r] - mn);
            s1[r] = __expf(s1[r] - mn);
            float rs = s0[r] + s1[r];
            rs += __shfl_xor(rs, 1); rs += __shfl_xor(rs, 2);
            rs += __shfl_xor(rs, 4); rs += __shfl_xor(rs, 8);
            l[r] = l[r] * fr[r] + rs;
        }
        f32x4 fv = {fr[0], fr[1], fr[2], fr[3]};
#pragma unroll
        for (int dt = 0; dt < 8; ++dt) o[dt] *= fv;
        // write P (D-layout) to LDS, XOR-swizzled, read back in A-layout
#pragma unroll
        for (int r = 0; r < 4; ++r) {
            int row = 4 * g + r;
            int sw = (row & 3) << 3;
            Pw[(row * 32 + rl) ^ sw]      = f2bf(s0[r]);
            Pw[(row * 32 + 16 + rl) ^ sw] = f2bf(s1[r]);
        }
        s16x8 pa = *(const s16x8*)(Pw + rl * 32 + ((g ^ (rl & 3)) << 3));
#pragma unroll
        for (int dt = 0; dt < 8; ++dt) {
            s16x8 vf = *(const s16x8*)(Vp + (long)(dt * 16 + rl) * T_ + k0 + g * 8);
            o[dt] = mfma16(pa, vf, o[dt]);
        }
    }
    // epilogue: normalize, gate, store
#pragma unroll
    for (int r = 0; r < 4; ++r) {
        int qi = qbase + 4 * g + r;
        long btr = (long)b * T_ + qi;
        float inv = 1.0f / l[r];
#pragma unroll
        for (int dt = 0; dt < 8; ++dt) {
            int d = dt * 16 + rl;
            float gate = bf2f(qkv[btr * NTOT + h * 256 + 128 + d]);
            float gv = 1.0f / (1.0f + __expf(-gate));
            AG[btr * (NH_ * HD_) + h * HD_ + d] = f2bf(o[dt][r] * inv * gv);
        }
    }
}

extern "C" void kernel_launch(void* const* d_in, const int* in_sizes, int n_in,
                              void* d_out, int out_size, void* d_ws, size_t ws_size,
                              hipStream_t stream) {
    (void)in_sizes; (void)n_in; (void)out_size; (void)ws_size;
    const float* hidden = (const float*)d_in[0];
    const float* cosp   = (const float*)d_in[1];
    const float* sinp   = (const float*)d_in[2];
    const float* w_q    = (const float*)d_in[5];
    const float* w_k    = (const float*)d_in[6];
    const float* w_v    = (const float*)d_in[7];
    const float* w_o    = (const float*)d_in[8];
    const float* qnw    = (const float*)d_in[9];
    const float* knw    = (const float*)d_in[10];

    short* ws      = (short*)d_ws;
    short* hiddenb = ws;                               // 4096*2048
    short* wqkvT   = hiddenb + (long)M_ * D_;          // 5120*2048
    short* woT     = wqkvT + (long)NTOT * D_;          // 2048*2048
    short* qkvb    = woT + (long)D_ * D_;              // 4096*5120
    short* Qb      = qkvb + (long)M_ * NTOT;           // 2*16*2048*128
    short* Kb      = Qb + (long)B_ * NH_ * T_ * HD_;   // 2*4*2048*128
    short* VTb     = Kb + (long)B_ * NKV_ * T_ * HD_;  // 2*4*2048*128
    short* AGb     = VTb + (long)B_ * NKV_ * T_ * HD_; // 4096*2048
    float* out     = (float*)d_out;

    dim3 tblk(32, 8);
    cast_f32_bf16<<<(M_ * D_) / 1024, 256, 0, stream>>>(hidden, hiddenb);
    transpose_cast<<<dim3(NQK / 32, D_ / 32), tblk, 0, stream>>>(w_q, wqkvT, D_, NQK);
    transpose_cast<<<dim3(NKC / 32, D_ / 32), tblk, 0, stream>>>(w_k, wqkvT + (long)NQK * D_, D_, NKC);
    transpose_cast<<<dim3(NKC / 32, D_ / 32), tblk, 0, stream>>>(w_v, wqkvT + (long)(NQK + NKC) * D_, D_, NKC);
    transpose_cast<<<dim3(D_ / 32, D_ / 32), tblk, 0, stream>>>(w_o, woT, D_, D_);

    gemm_bf16<short><<<(M_ / 128) * (NTOT / 128), 256, 0, stream>>>(
        hiddenb, wqkvT, qkvb, M_, NTOT, D_);

    postproc<<<(M_ * 20) / 4, 256, 0, stream>>>(qkvb, cosp, sinp, qnw, knw, Qb, Kb);
    transpose_v<<<dim3(T_ / 32, HD_ / 32, B_ * NKV_), tblk, 0, stream>>>(qkvb, VTb);

    fattn<<<B_ * NH_ * (T_ / 64), 256, 0, stream>>>(Qb, Kb, VTb, qkvb, AGb);

    gemm_bf16<float><<<(M_ / 128) * (D_ / 128), 256, 0, stream>>>(
        AGb, woT, out, M_, D_, D_);
}

// Round 2
// 673.317 us; speedup vs baseline: 1.1601x; 1.1601x over previous
//
#include <hip/hip_runtime.h>
#include <hip/hip_bf16.h>

#define DEVI __device__ __forceinline__

typedef __attribute__((ext_vector_type(4))) float f32x4;
typedef __attribute__((ext_vector_type(8))) short s16x8;
typedef __attribute__((ext_vector_type(4))) short s16x4;

static constexpr int B_   = 2;
static constexpr int T_   = 2048;
static constexpr int D_   = 2048;
static constexpr int NH_  = 16;
static constexpr int NKV_ = 4;
static constexpr int HD_  = 128;
static constexpr int M_   = B_ * T_;            // 4096 tokens
static constexpr int NQK  = NH_ * HD_ * 2;      // 4096 (q+gate)
static constexpr int NKC  = NKV_ * HD_;         // 512
static constexpr int NTOT = NQK + 2 * NKC;      // 5120
static constexpr float SCALE_ = 0.08838834764831845f; // HD^-0.5

DEVI short f2bf(float f) {
    __hip_bfloat16 h = __float2bfloat16(f);
    return __builtin_bit_cast(short, h);
}
DEVI float bf2f(short s) {
    unsigned int u = ((unsigned int)(unsigned short)s) << 16;
    return __builtin_bit_cast(float, u);
}
DEVI void store_out(short* p, float v) { *p = f2bf(v); }
DEVI void store_out(float* p, float v) { *p = v; }

DEVI f32x4 mfma16(s16x8 a, s16x8 b, f32x4 c) {
    return __builtin_amdgcn_mfma_f32_16x16x32_bf16(a, b, c, 0, 0, 0);
}

DEVI void gload_lds16(const void* g, void* l) {
    __builtin_amdgcn_global_load_lds(
        (const __attribute__((address_space(1))) void*)g,
        (__attribute__((address_space(3))) void*)l,
        16, 0, 0);
}

// ---------------- cast fp32 -> bf16 (vector x4) ----------------
__global__ void cast_f32_bf16(const float* __restrict__ in, short* __restrict__ out) {
    int i = (blockIdx.x * 256 + threadIdx.x) << 2;
    f32x4 v = *(const f32x4*)(in + i);
    s16x4 o;
#pragma unroll
    for (int j = 0; j < 4; ++j) o[j] = f2bf(v[j]);
    *(s16x4*)(out + i) = o;
}

// ---------------- transpose + cast: src fp32 (R,C) -> dst bf16 (C,R) ----------------
__global__ void transpose_cast(const float* __restrict__ src, short* __restrict__ dst,
                               int R, int C) {
    __shared__ float tile[32][33];
    int c0 = blockIdx.x << 5, r0 = blockIdx.y << 5;
    int tx = threadIdx.x, ty = threadIdx.y; // 32 x 8
#pragma unroll
    for (int i = 0; i < 32; i += 8)
        tile[ty + i][tx] = src[(long)(r0 + ty + i) * C + c0 + tx];
    __syncthreads();
#pragma unroll
    for (int i = 0; i < 32; i += 8)
        dst[(long)(c0 + ty + i) * R + r0 + tx] = f2bf(tile[tx][ty + i]);
}

// ---------------- GEMM: A(M,K) bf16 row-major  @  Bt(N,K) bf16 row-major -> C(M,N) ----------------
template <typename OUT>
__global__ __launch_bounds__(256, 2) void gemm_bf16(
    const short* __restrict__ A, const short* __restrict__ Bt,
    OUT* __restrict__ C, int M, int N, int K) {
    __shared__ __align__(16) short Asm[2][128 * 32];
    __shared__ __align__(16) short Bsm[2][128 * 32];
    int tid = threadIdx.x;
    int nbx = N >> 7;
    int bx = blockIdx.x % nbx, by = blockIdx.x / nbx;
    int row0 = by << 7, col0 = bx << 7;
    int lane = tid & 63, wave = tid >> 6;
    int wr = (wave >> 1) << 6, wc = (wave & 1) << 6;
    int g = lane >> 4, rl = lane & 15;
    int srow = tid >> 2, scol = (tid & 3) << 3;
    const short* Ag = A + (long)(row0 + srow) * K + scol;
    const short* Bg = Bt + (long)(col0 + srow) * K + scol;

    f32x4 acc[4][4];
#pragma unroll
    for (int i = 0; i < 4; ++i)
#pragma unroll
        for (int j = 0; j < 4; ++j) acc[i][j] = f32x4{0.f, 0.f, 0.f, 0.f};

    auto stage = [&](int buf, int kt) {
        int ko = kt << 5;
        gload_lds16(Ag + ko,            &Asm[buf][tid * 8]);
        gload_lds16(Ag + (K << 6) + ko, &Asm[buf][(tid + 256) * 8]);
        gload_lds16(Bg + ko,            &Bsm[buf][tid * 8]);
        gload_lds16(Bg + (K << 6) + ko, &Bsm[buf][(tid + 256) * 8]);
    };

    int KT = K >> 5;
    stage(0, 0);
    for (int kt = 0; kt < KT; ++kt) {
        __syncthreads();
        int buf = kt & 1;
        if (kt + 1 < KT) stage(buf ^ 1, kt + 1);
        const short* As = &Asm[buf][0];
        const short* Bs = &Bsm[buf][0];
        s16x8 af[4], bfr[4];
#pragma unroll
        for (int i = 0; i < 4; ++i) {
            af[i]  = *(const s16x8*)(As + (wr + i * 16 + rl) * 32 + g * 8);
            bfr[i] = *(const s16x8*)(Bs + (wc + i * 16 + rl) * 32 + g * 8);
        }
#pragma unroll
        for (int i = 0; i < 4; ++i)
#pragma unroll
            for (int j = 0; j < 4; ++j)
                acc[i][j] = mfma16(af[i], bfr[j], acc[i][j]);
    }
#pragma unroll
    for (int i = 0; i < 4; ++i)
#pragma unroll
        for (int j = 0; j < 4; ++j)
#pragma unroll
            for (int r = 0; r < 4; ++r) {
                int row = row0 + wr + i * 16 + 4 * g + r;
                int col = col0 + wc + j * 16 + rl;
                store_out(&C[(long)row * N + col], acc[i][j][r]);
            }
}

// ---------------- RMSNorm + RoPE for q and k heads ----------------
__global__ void postproc(const short* __restrict__ qkv, const float* __restrict__ cosp,
                         const float* __restrict__ sinp, const float* __restrict__ qw,
                         const float* __restrict__ kw, short* __restrict__ Q,
                         short* __restrict__ K) {
    int task = blockIdx.x * 4 + (threadIdx.x >> 6); // B*T*20 tasks
    int lane = threadIdx.x & 63;
    int bt = task / 20, sub = task - bt * 20;
    int b = bt >> 11, t = bt & (T_ - 1);
    bool isq = sub < 16;
    int h = isq ? sub : sub - 16;
    const short* src = qkv + (long)bt * NTOT + (isq ? h * 256 : NQK + h * HD_);
    const float* w = isq ? qw : kw;
    float x0 = bf2f(src[lane]);
    float x1 = bf2f(src[lane + 64]);
    float ss = x0 * x0 + x1 * x1;
    ss += __shfl_xor(ss, 32); ss += __shfl_xor(ss, 16); ss += __shfl_xor(ss, 8);
    ss += __shfl_xor(ss, 4);  ss += __shfl_xor(ss, 2);  ss += __shfl_xor(ss, 1);
    float rn = rsqrtf(ss * (1.0f / 128.0f) + 1e-6f);
    x0 *= rn * w[lane];
    x1 *= rn * w[lane + 64];
    float c0 = cosp[bt * HD_ + lane], c1 = cosp[bt * HD_ + lane + 64];
    float s0 = sinp[bt * HD_ + lane], s1 = sinp[bt * HD_ + lane + 64];
    float y0 = x0 * c0 - x1 * s0;
    float y1 = x1 * c1 + x0 * s1;
    short* dst;
    if (isq) {
        y0 *= SCALE_; y1 *= SCALE_;
        dst = Q + ((long)(b * NH_ + h) * T_ + t) * HD_;
    } else {
        dst = K + ((long)(b * NKV_ + h) * T_ + t) * HD_;
    }
    dst[lane]      = f2bf(y0);
    dst[lane + 64] = f2bf(y1);
}

// ---------------- V transpose: qkv v-cols -> VT (B,NKV,HD,T) ----------------
__global__ void transpose_v(const short* __restrict__ qkv, short* __restrict__ VT) {
    __shared__ short tile[32][33];
    int bh = blockIdx.z;
    int b = bh >> 2, h = bh & 3;
    int t0 = blockIdx.x << 5, d0 = blockIdx.y << 5;
    int tx = threadIdx.x, ty = threadIdx.y; // 32 x 8
    const short* src = qkv + (long)b * T_ * NTOT + NQK + NKC + h * HD_;
#pragma unroll
    for (int i = 0; i < 32; i += 8)
        tile[ty + i][tx] = src[(long)(t0 + ty + i) * NTOT + d0 + tx];
    __syncthreads();
    short* dst = VT + ((long)(b * NKV_ + h) * HD_ + d0) * T_ + t0;
#pragma unroll
    for (int i = 0; i < 32; i += 8)
        dst[(long)(ty + i) * T_ + tx] = tile[tx][ty + i];
}

// ---------------- flash attention helpers (swapped-QK layout) ----------------
// After S^T = mfma(Kfrag, Qfrag): lane(g,rl) holds S^T[key=k0+4g+r(+16)][q=qb+rl].
// Softmax stats (m,l) live in the rl-indexed q domain; O accumulator rows are
// q=4g+r, so the rescale factor and 1/l get a 4-shuffle transpose.
DEVI void softstep(f32x4& s0, f32x4& s1, float& m, float& l, f32x4 o[8],
                   s16x8& pa, int k0, int qb, int g, int rl) {
    if (k0 + 31 > qb) { // causal boundary tile
        int q = qb + rl;
#pragma unroll
        for (int r = 0; r < 4; ++r) {
            if (k0 + 4 * g + r > q)      s0[r] = -1e30f;
            if (k0 + 16 + 4 * g + r > q) s1[r] = -1e30f;
        }
    }
    float tm = fmaxf(fmaxf(fmaxf(s0[0], s0[1]), fmaxf(s0[2], s0[3])),
                     fmaxf(fmaxf(s1[0], s1[1]), fmaxf(s1[2], s1[3])));
    tm = fmaxf(tm, __shfl_xor(tm, 16));
    tm = fmaxf(tm, __shfl_xor(tm, 32));
    float mn = fmaxf(m, tm);
    float fr = __expf(m - mn);
    m = mn;
    float p[8];
#pragma unroll
    for (int r = 0; r < 4; ++r) {
        p[r]     = __expf(s0[r] - mn);
        p[4 + r] = __expf(s1[r] - mn);
    }
    float rs = ((p[0] + p[1]) + (p[2] + p[3])) + ((p[4] + p[5]) + (p[6] + p[7]));
    rs += __shfl_xor(rs, 16);
    rs += __shfl_xor(rs, 32);
    l = l * fr + rs;
    f32x4 fq;
#pragma unroll
    for (int r = 0; r < 4; ++r) fq[r] = __shfl(fr, 4 * g + r);
#pragma unroll
    for (int dt = 0; dt < 8; ++dt) o[dt] *= fq;
    s16x8 t;
#pragma unroll
    for (int i = 0; i < 8; ++i) t[i] = f2bf(p[i]);
    pa = t;
}

DEVI void epilogue(const f32x4 o[8], float l, int qb, int b, int h, int g, int rl,
                   const short* __restrict__ qkv, short* __restrict__ AG) {
    f32x4 linv;
#pragma unroll
    for (int r = 0; r < 4; ++r) linv[r] = 1.0f / __shfl(l, 4 * g + r);
#pragma unroll
    for (int r = 0; r < 4; ++r) {
        int qi = qb + 4 * g + r;
        long btr = (long)b * T_ + qi;
#pragma unroll
        for (int dt = 0; dt < 8; ++dt) {
            int d = dt * 16 + rl;
            float gate = bf2f(qkv[btr * NTOT + h * 256 + 128 + d]);
            float gv = 1.0f / (1.0f + __expf(-gate));
            AG[btr * (NH_ * HD_) + h * HD_ + d] = f2bf(o[dt][r] * linv[r] * gv);
        }
    }
}

// ---------------- causal GQA flash attention + sigmoid gate ----------------
// One wave owns TWO 16-row q-tiles: j and 127-j (same b,h) -> constant work
// per wave (perfect causal balance), shared K/V tile loads, 2 independent
// dependency chains for ILP. P never leaves registers (no LDS).
__global__ __launch_bounds__(256) void fattn(
    const short* __restrict__ Q, const short* __restrict__ K,
    const short* __restrict__ VT, const short* __restrict__ qkv,
    short* __restrict__ AG) {
    int wid  = blockIdx.x * 4 + (threadIdx.x >> 6); // 0..2047
    int lane = threadIdx.x & 63;
    int g = lane >> 4, rl = lane & 15;
    int j = wid & 63;
    int h = (wid >> 6) & 15;
    int b = wid >> 10;
    int kvh = h >> 2;
    int qbA = j << 4;
    int qbB = (127 - j) << 4;
    const short* Qp = Q + (long)(b * NH_ + h) * T_ * HD_;
    const short* Kp = K + (long)(b * NKV_ + kvh) * T_ * HD_;
    const short* Vp = VT + (long)(b * NKV_ + kvh) * HD_ * T_;

    s16x8 qfA[4], qfB[4];
#pragma unroll
    for (int c = 0; c < 4; ++c) {
        qfA[c] = *(const s16x8*)(Qp + (long)(qbA + rl) * HD_ + c * 32 + g * 8);
        qfB[c] = *(const s16x8*)(Qp + (long)(qbB + rl) * HD_ + c * 32 + g * 8);
    }

    f32x4 oA[8], oB[8];
#pragma unroll
    for (int dt = 0; dt < 8; ++dt) {
        oA[dt] = f32x4{0.f, 0.f, 0.f, 0.f};
        oB[dt] = f32x4{0.f, 0.f, 0.f, 0.f};
    }
    float mA = -1e30f, lA = 0.f, mB = -1e30f, lB = 0.f;

    int ntA = (qbA + 47) >> 5;
    int ntB = (qbB + 47) >> 5;

    for (int kt = 0; kt < ntB; ++kt) {
        int k0 = kt << 5;
        bool doA = kt < ntA;
        f32x4 sA0 = {0.f, 0.f, 0.f, 0.f}, sA1 = {0.f, 0.f, 0.f, 0.f};
        f32x4 sB0 = {0.f, 0.f, 0.f, 0.f}, sB1 = {0.f, 0.f, 0.f, 0.f};
#pragma unroll
        for (int c = 0; c < 4; ++c) {
            s16x8 kf0 = *(const s16x8*)(Kp + (long)(k0 + rl) * HD_ + c * 32 + g * 8);
            s16x8 kf1 = *(const s16x8*)(Kp + (long)(k0 + 16 + rl) * HD_ + c * 32 + g * 8);
            sB0 = mfma16(kf0, qfB[c], sB0);
            sB1 = mfma16(kf1, qfB[c], sB1);
            if (doA) {
                sA0 = mfma16(kf0, qfA[c], sA0);
                sA1 = mfma16(kf1, qfA[c], sA1);
            }
        }
        s16x8 paA, paB;
        softstep(sB0, sB1, mB, lB, oB, paB, k0, qbB, g, rl);
        if (doA) softstep(sA0, sA1, mA, lA, oA, paA, k0, qbA, g, rl);
#pragma unroll
        for (int dt = 0; dt < 8; ++dt) {
            const short* vp = Vp + (long)(dt * 16 + rl) * T_ + k0 + 4 * g;
            s16x4 v0 = *(const s16x4*)vp;
            s16x4 v1 = *(const s16x4*)(vp + 16);
            s16x8 vf = __builtin_shufflevector(v0, v1, 0, 1, 2, 3, 4, 5, 6, 7);
            oB[dt] = mfma16(paB, vf, oB[dt]);
            if (doA) oA[dt] = mfma16(paA, vf, oA[dt]);
        }
    }
    epilogue(oB, lB, qbB, b, h, g, rl, qkv, AG);
    epilogue(oA, lA, qbA, b, h, g, rl, qkv, AG);
}

extern "C" void kernel_launch(void* const* d_in, const int* in_sizes, int n_in,
                              void* d_out, int out_size, void* d_ws, size_t ws_size,
                              hipStream_t stream) {
    (void)in_sizes; (void)n_in; (void)out_size; (void)ws_size;
    const float* hidden = (const float*)d_in[0];
    const float* cosp   = (const float*)d_in[1];
    const float* sinp   = (const float*)d_in[2];
    const float* w_q    = (const float*)d_in[5];
    const float* w_k    = (const float*)d_in[6];
    const float* w_v    = (const float*)d_in[7];
    const float* w_o    = (const float*)d_in[8];
    const float* qnw    = (const float*)d_in[9];
    const float* knw    = (const float*)d_in[10];

    short* ws      = (short*)d_ws;
    short* hiddenb = ws;                               // 4096*2048
    short* wqkvT   = hiddenb + (long)M_ * D_;          // 5120*2048
    short* woT     = wqkvT + (long)NTOT * D_;          // 2048*2048
    short* qkvb    = woT + (long)D_ * D_;              // 4096*5120
    short* Qb      = qkvb + (long)M_ * NTOT;           // 2*16*2048*128
    short* Kb      = Qb + (long)B_ * NH_ * T_ * HD_;   // 2*4*2048*128
    short* VTb     = Kb + (long)B_ * NKV_ * T_ * HD_;  // 2*4*2048*128
    short* AGb     = VTb + (long)B_ * NKV_ * T_ * HD_; // 4096*2048
    float* out     = (float*)d_out;

    dim3 tblk(32, 8);
    cast_f32_bf16<<<(M_ * D_) / 1024, 256, 0, stream>>>(hidden, hiddenb);
    transpose_cast<<<dim3(NQK / 32, D_ / 32), tblk, 0, stream>>>(w_q, wqkvT, D_, NQK);
    transpose_cast<<<dim3(NKC / 32, D_ / 32), tblk, 0, stream>>>(w_k, wqkvT + (long)NQK * D_, D_, NKC);
    transpose_cast<<<dim3(NKC / 32, D_ / 32), tblk, 0, stream>>>(w_v, wqkvT + (long)(NQK + NKC) * D_, D_, NKC);
    transpose_cast<<<dim3(D_ / 32, D_ / 32), tblk, 0, stream>>>(w_o, woT, D_, D_);

    gemm_bf16<short><<<(M_ / 128) * (NTOT / 128), 256, 0, stream>>>(
        hiddenb, wqkvT, qkvb, M_, NTOT, D_);

    postproc<<<(M_ * 20) / 4, 256, 0, stream>>>(qkvb, cosp, sinp, qnw, knw, Qb, Kb);
    transpose_v<<<dim3(T_ / 32, HD_ / 32, B_ * NKV_), tblk, 0, stream>>>(qkvb, VTb);

    fattn<<<512, 256, 0, stream>>>(Qb, Kb, VTb, qkvb, AGb);

    gemm_bf16<float><<<(M_ / 128) * (D_ / 128), 256, 0, stream>>>(
        AGb, woT, out, M_, D_, D_);
}